// Round 3
// baseline (307.439 us; speedup 1.0000x reference)
//
#include <hip/hip_runtime.h>
#include <hip/hip_fp16.h>

// graph_56006373539875: per-edge spring-force scatter.
// R1: device atomics write-through -> 1881us.
// R2: LDS-privatized 8-range scan -> 240us, bound by L2 request rate of the
//     per-hit points gathers (6 scattered dwords x 23% hit x 51.2M exams).
// R3: phase A materializes per-edge force vectors ONCE (packed 12B gathers),
//     phase B redundant scan only streams ea/eb + one 16B load per hit.
//
// NR=8 node ranges x 12500 nodes (150KB LDS/block, 1 block/CU)
// NB=32 edge chunks; grid 256 = 1 block/CU.

#define NR 8
#define NB 32
#define BLOCK 1024
#define ABLOCK 256

struct __attribute__((packed, aligned(4))) F3 { float x, y, z; };

// ---------------- phase A: per-edge force vector ----------------
template <int HALF>
__global__ __launch_bounds__(ABLOCK) void force_kernel(
    const float* __restrict__ points, const float* __restrict__ force,
    const int* __restrict__ ea, const int* __restrict__ eb,
    void* __restrict__ fout, int n_edges)
{
    const F3* __restrict__ P = (const F3*)points;
    int stride = gridDim.x * ABLOCK;
    for (int e = blockIdx.x * ABLOCK + threadIdx.x; e < n_edges; e += stride) {
        int a = ea[e], b = eb[e];
        F3 pa = P[a];
        F3 pb = P[b];
        float vx = pb.x - pa.x, vy = pb.y - pa.y, vz = pb.z - pa.z;
        float s = -force[e] * rsqrtf(vx * vx + vy * vy + vz * vz);
        if (HALF) {
            ushort4 q;
            q.x = __half_as_ushort(__float2half(s * vx));
            q.y = __half_as_ushort(__float2half(s * vy));
            q.z = __half_as_ushort(__float2half(s * vz));
            q.w = 0;
            ((ushort4*)fout)[e] = q;
        } else {
            ((float4*)fout)[e] = make_float4(s * vx, s * vy, s * vz, 0.f);
        }
    }
}

// ---------------- phase B: privatized scatter, no gathers ----------------
template <int HALF>
__global__ __launch_bounds__(BLOCK) void scatter_kernel(
    const int* __restrict__ ea, const int* __restrict__ eb,
    const void* __restrict__ fbuf,
    float* __restrict__ partial,     // [NB][n_points*3]
    int n_edges, int n_points, int range)
{
    extern __shared__ float lds[];   // range*3
    const int r = blockIdx.x / NB;
    const int c = blockIdx.x % NB;
    const int node0 = r * range;
    const int nwords = range * 3;

    for (int w = threadIdx.x; w < nwords; w += BLOCK) lds[w] = 0.0f;
    __syncthreads();

    const int chunk = (n_edges + NB - 1) / NB;
    const int e0 = c * chunk;
    const int e1 = min(n_edges, e0 + chunk);

    for (int e = e0 + (int)threadIdx.x; e < e1; e += BLOCK) {
        int a = ea[e];
        int b = eb[e];
        int la = a - node0;
        int lb = b - node0;
        bool ha = (unsigned)la < (unsigned)range;
        bool hb = (unsigned)lb < (unsigned)range;
        if (!(ha || hb)) continue;

        float fx, fy, fz;
        if (HALF) {
            ushort4 q = ((const ushort4*)fbuf)[e];   // 8B aligned, 1 req
            fx = __half2float(__ushort_as_half(q.x));
            fy = __half2float(__ushort_as_half(q.y));
            fz = __half2float(__ushort_as_half(q.z));
        } else {
            float4 q = ((const float4*)fbuf)[e];     // 16B aligned, 1 req
            fx = q.x; fy = q.y; fz = q.z;
        }
        if (ha) {
            atomicAdd(&lds[la * 3 + 0], fx);
            atomicAdd(&lds[la * 3 + 1], fy);
            atomicAdd(&lds[la * 3 + 2], fz);
        }
        if (hb) {
            atomicAdd(&lds[lb * 3 + 0], -fx);
            atomicAdd(&lds[lb * 3 + 1], -fy);
            atomicAdd(&lds[lb * 3 + 2], -fz);
        }
    }
    __syncthreads();

    const int base = node0 * 3;
    const int total = n_points * 3;
    float* dst = partial + (size_t)c * (size_t)total + base;
    for (int w = threadIdx.x; w < nwords; w += BLOCK)
        if (base + w < total) dst[w] = lds[w];
}

// ---------------- R2 fallback: fused scan (gathers inside) ----------------
__global__ __launch_bounds__(BLOCK) void edge_scan_kernel(
    const float* __restrict__ points, const float* __restrict__ force,
    const int* __restrict__ ea, const int* __restrict__ eb,
    float* __restrict__ partial, float* __restrict__ out,
    int n_edges, int n_points, int range, int atomic_mode)
{
    extern __shared__ float lds[];
    const int r = blockIdx.x / NB;
    const int c = blockIdx.x % NB;
    const int node0 = r * range;
    const int nwords = range * 3;

    for (int w = threadIdx.x; w < nwords; w += BLOCK) lds[w] = 0.0f;
    __syncthreads();

    const int chunk = (n_edges + NB - 1) / NB;
    const int e0 = c * chunk;
    const int e1 = min(n_edges, e0 + chunk);

    for (int e = e0 + (int)threadIdx.x; e < e1; e += BLOCK) {
        int a = ea[e], b = eb[e];
        int la = a - node0, lb = b - node0;
        bool ha = (unsigned)la < (unsigned)range;
        bool hb = (unsigned)lb < (unsigned)range;
        if (!(ha || hb)) continue;
        float ax = points[3*a+0], ay = points[3*a+1], az = points[3*a+2];
        float bx = points[3*b+0], by = points[3*b+1], bz = points[3*b+2];
        float vx = bx-ax, vy = by-ay, vz = bz-az;
        float s = -force[e] * rsqrtf(vx*vx+vy*vy+vz*vz);
        float fx = s*vx, fy = s*vy, fz = s*vz;
        if (ha) { atomicAdd(&lds[la*3+0], fx); atomicAdd(&lds[la*3+1], fy); atomicAdd(&lds[la*3+2], fz); }
        if (hb) { atomicAdd(&lds[lb*3+0], -fx); atomicAdd(&lds[lb*3+1], -fy); atomicAdd(&lds[lb*3+2], -fz); }
    }
    __syncthreads();

    const int base = node0 * 3;
    const int total = n_points * 3;
    if (atomic_mode) {
        for (int w = threadIdx.x; w < nwords; w += BLOCK)
            if (base + w < total) atomicAdd(&out[base + w], lds[w]);
    } else {
        float* dst = partial + (size_t)c * (size_t)total + base;
        for (int w = threadIdx.x; w < nwords; w += BLOCK)
            if (base + w < total) dst[w] = lds[w];
    }
}

__global__ void reduce_kernel(const float* __restrict__ ext,
                              const float* __restrict__ partial,
                              float* __restrict__ out, int n)
{
    int i = blockIdx.x * blockDim.x + threadIdx.x;
    if (i >= n) return;
    float s = ext[i];
#pragma unroll
    for (int c = 0; c < NB; ++c) s += partial[(size_t)c * (size_t)n + i];
    out[i] = s;
}

extern "C" void kernel_launch(void* const* d_in, const int* in_sizes, int n_in,
                              void* d_out, int out_size, void* d_ws, size_t ws_size,
                              hipStream_t stream) {
    const float* points = (const float*)d_in[0];
    const float* ext_f  = (const float*)d_in[1];
    const float* force  = (const float*)d_in[2];
    const int*   ea     = (const int*)d_in[3];
    const int*   eb     = (const int*)d_in[4];
    float* out = (float*)d_out;
    char*  ws  = (char*)d_ws;

    const int n_edges  = in_sizes[2];
    const int total    = out_size;                       // n_points*3
    const int n_points = total / 3;
    const int range    = (n_points + NR - 1) / NR;       // 12500
    const size_t lds_bytes    = (size_t)range * 3 * sizeof(float);   // 150000
    const size_t partial_bytes = (size_t)NB * (size_t)total * sizeof(float);
    const size_t f4_bytes = (size_t)n_edges * 16;
    const size_t h4_bytes = (size_t)n_edges * 8;

    hipFuncSetAttribute((const void*)scatter_kernel<0>,
                        hipFuncAttributeMaxDynamicSharedMemorySize, (int)lds_bytes);
    hipFuncSetAttribute((const void*)scatter_kernel<1>,
                        hipFuncAttributeMaxDynamicSharedMemorySize, (int)lds_bytes);
    hipFuncSetAttribute((const void*)edge_scan_kernel,
                        hipFuncAttributeMaxDynamicSharedMemorySize, (int)lds_bytes);

    const int ablocks = min((n_edges + ABLOCK - 1) / ABLOCK, 4096);
    const int rb = 256;

    if (ws_size >= f4_bytes + partial_bytes) {
        // tier 1: fp32 force vectors
        void*  fbuf    = (void*)ws;
        float* partial = (float*)(ws + f4_bytes);
        force_kernel<0><<<ablocks, ABLOCK, 0, stream>>>(points, force, ea, eb, fbuf, n_edges);
        scatter_kernel<0><<<NR * NB, BLOCK, lds_bytes, stream>>>(
            ea, eb, fbuf, partial, n_edges, n_points, range);
        reduce_kernel<<<(total + rb - 1) / rb, rb, 0, stream>>>(ext_f, partial, out, total);
    } else if (ws_size >= h4_bytes + partial_bytes) {
        // tier 2: fp16 force vectors
        void*  fbuf    = (void*)ws;
        float* partial = (float*)(ws + h4_bytes);
        force_kernel<1><<<ablocks, ABLOCK, 0, stream>>>(points, force, ea, eb, fbuf, n_edges);
        scatter_kernel<1><<<NR * NB, BLOCK, lds_bytes, stream>>>(
            ea, eb, fbuf, partial, n_edges, n_points, range);
        reduce_kernel<<<(total + rb - 1) / rb, rb, 0, stream>>>(ext_f, partial, out, total);
    } else if (ws_size >= partial_bytes) {
        // tier 3: R2 fused path
        float* partial = (float*)ws;
        edge_scan_kernel<<<NR * NB, BLOCK, lds_bytes, stream>>>(
            points, force, ea, eb, partial, out, n_edges, n_points, range, 0);
        reduce_kernel<<<(total + rb - 1) / rb, rb, 0, stream>>>(ext_f, partial, out, total);
    } else {
        // tier 4: atomic flush
        hipMemcpyAsync(d_out, (const void*)ext_f, (size_t)total * sizeof(float),
                       hipMemcpyDeviceToDevice, stream);
        edge_scan_kernel<<<NR * NB, BLOCK, lds_bytes, stream>>>(
            points, force, ea, eb, nullptr, out, n_edges, n_points, range, 1);
    }
}